// Round 14
// baseline (764.283 us; speedup 1.0000x reference)
//
#include <hip/hip_runtime.h>
#include <hip/hip_bf16.h>

// StockFormer forward, MI355X — bf16 MFMA pipeline v8
// (transposed-PV attention: no P LDS tile, ds_bpermute P-frags, 34.3KB LDS).
// B=4, S=256, N=128, F=64, D=E=128, NH=4, HD=32, BN=512, M=131072. Output f32.
typedef __attribute__((ext_vector_type(8))) short short8v;   // 8 bf16 (4 VGPR)
typedef __attribute__((ext_vector_type(4))) short short4v;   // 4 bf16 (2 VGPR)
typedef __attribute__((ext_vector_type(4))) float f32x4;
typedef __hip_bfloat16 bh;

constexpr long SF_ELEMS = 131072L * 128;   // elements per ws slot (bf16 -> 32 MiB)
#define MFMA16(a, b, c) __builtin_amdgcn_mfma_f32_16x16x32_bf16((a), (b), (c), 0, 0, 0)
#define EXP2F(x) __builtin_amdgcn_exp2f(x)

__device__ __forceinline__ short bh_bits(float x) {
  bh h = __float2bfloat16(x);
  return *reinterpret_cast<short*>(&h);
}
__device__ __forceinline__ int pack2bh(float a, float b) {
  return (int)(((unsigned)(unsigned short)bh_bits(a)) |
               (((unsigned)(unsigned short)bh_bits(b)) << 16));
}

// Arena (bf16 elems): 0 ta_w_in | 49152 ta_w_o | 65536 pl | 81920 ph | 98304 ac_w_in |
// 147456 ac_w_o | 163840 as_w_in | 212992 as_w_o | 229376 wrep | 278528 end. Then PE f32.

// ---------------------------------------------------------------------------
__global__ __launch_bounds__(256) void sf_wcvt(const float* __restrict__ s0, const float* __restrict__ s1,
                                               const float* __restrict__ s2, const float* __restrict__ s3,
                                               const float* __restrict__ s4, const float* __restrict__ s5,
                                               const float* __restrict__ s6, const float* __restrict__ s7,
                                               const float* __restrict__ cw,
                                               bh* __restrict__ dst, float* __restrict__ pe) {
  int i = blockIdx.x * 256 + threadIdx.x;
  if (i >= 278528) {                           // PE table: pe[s][e]
    int j = i - 278528;
    if (j < 32768) {
      int e = j & 127, s = j >> 7;
      int ii = e >> 1;
      float dv = expf(-0.0719557945041855f * (float)(2 * ii));
      float ang = (float)s * dv;
      pe[j] = (e & 1) ? cosf(ang) : sinf(ang);
    }
    return;
  }
  float v;
  if      (i <  49152) v = s0[i];
  else if (i <  65536) v = s1[i - 49152];
  else if (i <  81920) v = s2[i - 65536];
  else if (i <  98304) v = s3[i - 81920];
  else if (i < 147456) v = s4[i - 98304];
  else if (i < 163840) v = s5[i - 147456];
  else if (i < 212992) v = s6[i - 163840];
  else if (i < 229376) v = s7[i - 212992];
  else {                                       // conv_w repack: wrep[tap][dch][ic]
    int j = i - 229376;
    int tap = j >> 14, rem = j & 16383;
    v = cw[rem * 3 + tap];
  }
  dst[i] = __float2bfloat16(v);
}

// ---------------------------------------------------------------------------
__global__ __launch_bounds__(256) void sf_buildzx(const float* __restrict__ x,
                                                  const float* __restrict__ pe,
                                                  bh* __restrict__ z,
                                                  bh* __restrict__ xh) {
  long i = (long)blockIdx.x * 256 + threadIdx.x;
  if (i >= SF_ELEMS) return;
  int e = (int)(i & 127);
  int s = (int)((i >> 7) & 255);
  int r = (int)(i >> 15);
  int b = r >> 7, stk = r & 127;
  float zv, hv;
  if (e < 64) {
    float val = x[(((long)b * 256 + s) * 128 + stk) * 64 + e];
    zv = val; hv = val;
  } else {
    int f = e - 64;
    int t2 = s >> 1;
    float a0 = x[(((long)b * 256 + 2 * t2) * 128 + stk) * 64 + f];
    float a1 = x[(((long)b * 256 + 2 * t2 + 1) * 128 + stk) * 64 + f];
    zv = 0.5f * (a0 + a1);
    float d = 0.5f * (a0 - a1);
    hv = (s & 1) ? -d : d;
  }
  z[i] = __float2bfloat16(zv + pe[s * 128 + e]);
  xh[i] = __float2bfloat16(hv);
}

// ---------------------------------------------------------------------------
// Attention body v8: fused projections; transposed PV (O^T = Vt·P^T) with
// register P-frags via ds_bpermute — no P LDS tile, no write->read round trip.
// Q-proj scratch overlays Ks rows [w*64, w*64+16) (wave-in-order DS).
// ---------------------------------------------------------------------------
__device__ __forceinline__ void attn_body(const bh* Qsrc, const bh* KVsrc,
                                          const bh* __restrict__ Win,
                                          const float* __restrict__ bin,
                                          bh* __restrict__ O, int bn, int h,
                                          bh (*Ks)[36], bh (*Vt)[260]) {
  const int t = threadIdx.x, lane = t & 63, w = t >> 6;
  const int lr = lane & 15, lg = lane >> 4;
  const long R0 = (long)bn * 256;
  const int ch = h * 32;
  const f32x4 z4 = {0.f, 0.f, 0.f, 0.f};
  const float SC2 = 0.2550351f;   // (1/sqrt(32)) * log2(e)
  short8v aq[4];
  // ---- Q projection through Ks-row scratch, immediate readback ----
  {
    bh* scr = &Ks[w * 64][0];
    short8v wq[2][4];
#pragma unroll
    for (int n = 0; n < 2; ++n)
#pragma unroll
      for (int ks = 0; ks < 4; ++ks)
        wq[n][ks] = *reinterpret_cast<const short8v*>(Win + (long)(ch + n * 16 + lr) * 128 + ks * 32 + lg * 8);
#pragma unroll
    for (int m2 = 0; m2 < 4; ++m2) {
      short8v asv[4];
#pragma unroll
      for (int ks = 0; ks < 4; ++ks)
        asv[ks] = *reinterpret_cast<const short8v*>(Qsrc + (R0 + w * 64 + m2 * 16 + lr) * 128 + ks * 32 + lg * 8);
#pragma unroll
      for (int n = 0; n < 2; ++n) {
        f32x4 acc = z4;
#pragma unroll
        for (int ks = 0; ks < 4; ++ks) acc = MFMA16(asv[ks], wq[n][ks], acc);
        float bb = bin[ch + n * 16 + lr];
#pragma unroll
        for (int r = 0; r < 4; ++r)
          scr[(4 * lg + r) * 36 + n * 16 + lr] = __float2bfloat16((acc[r] + bb) * SC2);
      }
      aq[m2] = *reinterpret_cast<const short8v*>(&scr[lr * 36 + lg * 8]);
    }
  }
  // ---- K,V projection (64 rows per wave; shared A-frags) ----
  {
    short8v wk[2][4], wv[2][4];
#pragma unroll
    for (int n = 0; n < 2; ++n)
#pragma unroll
      for (int ks = 0; ks < 4; ++ks) {
        wk[n][ks] = *reinterpret_cast<const short8v*>(Win + (long)(128 + ch + n * 16 + lr) * 128 + ks * 32 + lg * 8);
        wv[n][ks] = *reinterpret_cast<const short8v*>(Win + (long)(256 + ch + n * 16 + lr) * 128 + ks * 32 + lg * 8);
      }
#pragma unroll
    for (int m2 = 0; m2 < 4; ++m2) {
      short8v asv[4];
#pragma unroll
      for (int ks = 0; ks < 4; ++ks)
        asv[ks] = *reinterpret_cast<const short8v*>(KVsrc + (R0 + w * 64 + m2 * 16 + lr) * 128 + ks * 32 + lg * 8);
#pragma unroll
      for (int n = 0; n < 2; ++n) {
        f32x4 ak = z4, av = z4;
#pragma unroll
        for (int ks = 0; ks < 4; ++ks) {
          ak = MFMA16(asv[ks], wk[n][ks], ak);
          av = MFMA16(asv[ks], wv[n][ks], av);
        }
        float bk = bin[128 + ch + n * 16 + lr];
        float bv = bin[256 + ch + n * 16 + lr];
#pragma unroll
        for (int r = 0; r < 4; ++r)
          Ks[w * 64 + m2 * 16 + 4 * lg + r][n * 16 + lr] = __float2bfloat16(ak[r] + bk);
        short4v pv;
#pragma unroll
        for (int r = 0; r < 4; ++r) pv[r] = bh_bits(av[r] + bv);
        *reinterpret_cast<short4v*>(&Vt[n * 16 + lr][w * 64 + m2 * 16 + 4 * lg]) = pv;
      }
    }
  }
  __syncthreads();
  // ---- attention loop: S^T = K·Q^T; P-frags in registers via bpermute ----
  // bpermute src lanes: frag reg j of lane (lr,lg) pulls pk2[2ks+(lg>>1)][j&1]
  // from lane (2*(lg&1)+(j>>1))*16+lr.
  const int addrA = ((2 * (lg & 1)) * 16 + lr) * 4;
  const int addrB = addrA + 64;
  const bool hiHalf = (lg >= 2);
  f32x4 Oacc[4][2];
  float psum[4] = {0.f, 0.f, 0.f, 0.f};
#pragma unroll
  for (int mt = 0; mt < 4; ++mt) { Oacc[mt][0] = z4; Oacc[mt][1] = z4; }
#pragma unroll
  for (int kt = 0; kt < 4; ++kt) {
    short8v bvf[2][2];
#pragma unroll
    for (int dt = 0; dt < 2; ++dt)
#pragma unroll
      for (int ks = 0; ks < 2; ++ks)
        bvf[dt][ks] = *reinterpret_cast<const short8v*>(&Vt[dt * 16 + lr][kt * 64 + ks * 32 + lg * 8]);
#pragma unroll
    for (int mt = 0; mt < 4; ++mt) {
      f32x4 st[4];
#pragma unroll
      for (int nt = 0; nt < 4; ++nt) {
        short8v bk = *reinterpret_cast<const short8v*>(&Ks[kt * 64 + nt * 16 + lr][lg * 8]);
        st[nt] = MFMA16(bk, aq[mt], z4);     // S^T·SC2 = K·(Q*SC2)^T
      }
      int pk2[4][2];
      float ps = 0.f;
#pragma unroll
      for (int nt = 0; nt < 4; ++nt) {
        float p0 = EXP2F(st[nt][0]);
        float p1 = EXP2F(st[nt][1]);
        float p2 = EXP2F(st[nt][2]);
        float p3 = EXP2F(st[nt][3]);
        ps += (p0 + p1) + (p2 + p3);
        pk2[nt][0] = pack2bh(p0, p1);
        pk2[nt][1] = pack2bh(p2, p3);
      }
      psum[mt] += ps;
#pragma unroll
      for (int ks = 0; ks < 2; ++ks) {
        union { int i[4]; short8v v; } pf;
#pragma unroll
        for (int j = 0; j < 4; ++j) {
          int ad = (j < 2) ? addrA : addrB;
          int lo = __builtin_amdgcn_ds_bpermute(ad, pk2[2 * ks][j & 1]);
          int hi = __builtin_amdgcn_ds_bpermute(ad, pk2[2 * ks + 1][j & 1]);
          pf.i[j] = hiHalf ? hi : lo;
        }
        Oacc[mt][0] = MFMA16(bvf[0][ks], pf.v, Oacc[mt][0]);   // O^T = Vt·P^T
        Oacc[mt][1] = MFMA16(bvf[1][ks], pf.v, Oacc[mt][1]);
      }
    }
  }
  // ---- epilogue: lane-local 1/l (q = lr); packed 8B O stores ----
#pragma unroll
  for (int mt = 0; mt < 4; ++mt) {
    float ps = psum[mt];
    ps += __shfl_xor(ps, 16, 64);
    ps += __shfl_xor(ps, 32, 64);
    float inv = 1.f / ps;
    long row = R0 + w * 64 + mt * 16 + lr;
#pragma unroll
    for (int dt = 0; dt < 2; ++dt) {
      short4v ov;
#pragma unroll
      for (int r = 0; r < 4; ++r) ov[r] = bh_bits(Oacc[mt][dt][r] * inv);
      *reinterpret_cast<short4v*>(O + row * 128 + ch + dt * 16 + 4 * lg) = ov;
    }
  }
}

// XCD-grouped mapping (4 heads of one bn on the same XCD). Bijective on [0,2048).
__device__ __forceinline__ void map_bnh(int g, int& bn, int& h) {
  int xcd = g & 7, slot = g >> 3;
  bn = xcd + 8 * (slot >> 2);
  h = slot & 3;
}

// single attention (encoder)
__global__ __launch_bounds__(256, 4) void sf_attnp(const bh* Qsrc, const bh* KVsrc,
                                                   const bh* __restrict__ Win,
                                                   const float* __restrict__ bin,
                                                   bh* __restrict__ O) {
  __shared__ bh Ks[256][36];
  __shared__ bh Vt[32][260];
  int bn, h;
  map_bnh(blockIdx.x, bn, h);
  attn_body(Qsrc, KVsrc, Win, bin, O, bn, h, Ks, Vt);
}

// merged cross (g<2048) + self (g>=2048) attention
__global__ __launch_bounds__(256, 4) void sf_attnp2(const bh* Qc, const bh* KVc,
                                                    const bh* __restrict__ Wc, const float* __restrict__ bc,
                                                    bh* __restrict__ Oc,
                                                    const bh* Qs, const bh* KVs,
                                                    const bh* __restrict__ Wsl, const float* __restrict__ bsl,
                                                    bh* __restrict__ Os) {
  __shared__ bh Ks[256][36];
  __shared__ bh Vt[32][260];
  int g = blockIdx.x, bn, h;
  if (g < 2048) {
    map_bnh(g, bn, h);
    attn_body(Qc, KVc, Wc, bc, Oc, bn, h, Ks, Vt);
  } else {
    map_bnh(g - 2048, bn, h);
    attn_body(Qs, KVs, Wsl, bsl, Os, bn, h, Ks, Vt);
  }
}

// ---------------------------------------------------------------------------
// Merged decoder-prep launch:
//  blocks [0,1024):   encdec  X=encattn -> y_l -> q_l (stored) -> y_l2 -> lheads
//  blocks [1024,2048): convm_kh  xh -> conv+ReLU (y_h tile in LDS) -> ph-GEMM -> k_h
// ---------------------------------------------------------------------------
__global__ __launch_bounds__(256) void sf_dec(const bh* __restrict__ X,
                                              const bh* __restrict__ Wo, const float* __restrict__ bo,
                                              const bh* __restrict__ Wpl, const float* __restrict__ bpl,
                                              const float* __restrict__ rw, const float* __restrict__ rb,
                                              const float* __restrict__ cw, const float* __restrict__ cb,
                                              bh* __restrict__ Yq, float* __restrict__ out,
                                              long off_reg, long off_cla,
                                              const bh* __restrict__ Xh,
                                              const bh* __restrict__ Wr, const float* __restrict__ cbias,
                                              const bh* __restrict__ Wph, const float* __restrict__ bph,
                                              bh* __restrict__ KH) {
  __shared__ bh Lw[4][32][140];
  __shared__ float hw[3][128];
  const int t = threadIdx.x, lane = t & 63, w = t >> 6;
  const int lr = lane & 15, lg = lane >> 4;
  const f32x4 z4 = {0.f, 0.f, 0.f, 0.f};
  if (blockIdx.x < 1024) {
    // ================= encdec =================
    const long R0 = (long)blockIdx.x * 128 + w * 32;
    if (t < 128) { hw[0][t] = rw[t]; hw[1][t] = cw[t]; hw[2][t] = cw[128 + t]; }
    {
      short8v a[2][4];
#pragma unroll
      for (int ks = 0; ks < 4; ++ks) {
        a[0][ks] = *reinterpret_cast<const short8v*>(X + (R0 + lr) * 128 + ks * 32 + lg * 8);
        a[1][ks] = *reinterpret_cast<const short8v*>(X + (R0 + 16 + lr) * 128 + ks * 32 + lg * 8);
      }
      f32x4 acc[2][8];
#pragma unroll
      for (int m = 0; m < 2; ++m)
#pragma unroll
        for (int n = 0; n < 8; ++n) acc[m][n] = z4;
#pragma unroll
      for (int ks = 0; ks < 4; ++ks)
#pragma unroll
        for (int n = 0; n < 8; ++n) {
          short8v b = *reinterpret_cast<const short8v*>(Wo + (long)(n * 16 + lr) * 128 + ks * 32 + lg * 8);
          acc[0][n] = MFMA16(a[0][ks], b, acc[0][n]);
          acc[1][n] = MFMA16(a[1][ks], b, acc[1][n]);
        }
#pragma unroll
      for (int n = 0; n < 8; ++n) {
        float bv = bo[n * 16 + lr];
#pragma unroll
        for (int m = 0; m < 2; ++m)
#pragma unroll
          for (int r = 0; r < 4; ++r)
            Lw[w][m * 16 + 4 * lg + r][n * 16 + lr] = __float2bfloat16(acc[m][n][r] + bv);
      }
    }
#pragma unroll
    for (int stage = 0; stage < 2; ++stage) {
      short8v a[2][4];
#pragma unroll
      for (int ks = 0; ks < 4; ++ks) {
        a[0][ks] = *reinterpret_cast<const short8v*>(&Lw[w][lr][ks * 32 + lg * 8]);
        a[1][ks] = *reinterpret_cast<const short8v*>(&Lw[w][16 + lr][ks * 32 + lg * 8]);
      }
      f32x4 acc[2][8];
#pragma unroll
      for (int m = 0; m < 2; ++m)
#pragma unroll
        for (int n = 0; n < 8; ++n) acc[m][n] = z4;
#pragma unroll
      for (int ks = 0; ks < 4; ++ks)
#pragma unroll
        for (int n = 0; n < 8; ++n) {
          short8v b = *reinterpret_cast<const short8v*>(Wpl + (long)(n * 16 + lr) * 128 + ks * 32 + lg * 8);
          acc[0][n] = MFMA16(a[0][ks], b, acc[0][n]);
          acc[1][n] = MFMA16(a[1][ks], b, acc[1][n]);
        }
#pragma unroll
      for (int n = 0; n < 8; ++n) {
        float bv = bpl[n * 16 + lr];
#pragma unroll
        for (int m = 0; m < 2; ++m)
#pragma unroll
          for (int r = 0; r < 4; ++r)
            Lw[w][m * 16 + 4 * lg + r][n * 16 + lr] = __float2bfloat16(acc[m][n][r] + bv);
      }
      if (stage == 0) {
#pragma unroll
        for (int c = 0; c < 8; ++c) {
          int row_l = c * 4 + lg;
          short8v v = *reinterpret_cast<const short8v*>(&Lw[w][row_l][lr * 8]);
          *reinterpret_cast<short8v*>(Yq + (R0 + row_l) * 128 + lr * 8) = v;
        }
      }
    }
    __syncthreads();
    {
      const int rr = lane >> 1, hh = lane & 1;
      float d0 = 0.f, d1 = 0.f, d2 = 0.f;
#pragma unroll
      for (int j = 0; j < 8; ++j) {
        short8v v8 = *reinterpret_cast<const short8v*>(&Lw[w][rr][hh * 64 + j * 8]);
        const bh* vv = reinterpret_cast<const bh*>(&v8);
#pragma unroll
        for (int k = 0; k < 8; ++k) {
          float f = __bfloat162float(vv[k]);
          int c = hh * 64 + j * 8 + k;
          d0 = fmaf(f, hw[0][c], d0);
          d1 = fmaf(f, hw[1][c], d1);
          d2 = fmaf(f, hw[2][c], d2);
        }
      }
      d0 += __shfl_xor(d0, 1, 64);
      d1 += __shfl_xor(d1, 1, 64);
      d2 += __shfl_xor(d2, 1, 64);
      if (hh == 0) {
        long row = R0 + rr;
        d0 += rb[0]; d1 += cb[0]; d2 += cb[1];
        float mx = fmaxf(d1, d2);
        float e1 = __expf(d1 - mx), e2 = __expf(d2 - mx);
        float inv = 1.f / (e1 + e2);
        out[off_reg + row] = d0;
        out[off_cla + row * 2] = e1 * inv;
        out[off_cla + row * 2 + 1] = e2 * inv;
      }
    }
  } else {
    // ================= convm + k_h chain =================
    int bid = blockIdx.x - 1024;
    const int bnc = bid >> 1;
    const int half = bid & 1;
    const int b = bnc >> 7, stk = bnc & 127;
    const int R0 = half * 128 + w * 32;
    const short8v zf = {0, 0, 0, 0, 0, 0, 0, 0};
    f32x4 acc[2][8];
#pragma unroll
    for (int m = 0; m < 2; ++m)
#pragma unroll
      for (int n = 0; n < 8; ++n) acc[m][n] = z4;
#pragma unroll
    for (int tap = 0; tap < 3; ++tap) {
      const int shift = 2 * tap - 2;
#pragma unroll
      for (int ks = 0; ks < 4; ++ks) {
        int s0 = R0 + lr + shift;
        int s1 = s0 + 16;
        short8v a0 = zf, a1 = zf;
        if ((unsigned)s0 < 256u)
          a0 = *reinterpret_cast<const short8v*>(Xh + ((long)bnc * 256 + s0) * 128 + ks * 32 + lg * 8);
        if ((unsigned)s1 < 256u)
          a1 = *reinterpret_cast<const short8v*>(Xh + ((long)bnc * 256 + s1) * 128 + ks * 32 + lg * 8);
#pragma unroll
        for (int n = 0; n < 8; ++n) {
          short8v bb = *reinterpret_cast<const short8v*>(Wr + (long)tap * 16384 + (long)(n * 16 + lr) * 128 + ks * 32 + lg * 8);
          acc[0][n] = MFMA16(a0, bb, acc[0][n]);
          acc[1][n] = MFMA16(a1, bb, acc[1][n]);
        }
      }
    }
#pragma unroll
    for (int n = 0; n < 8; ++n) {
      float bv = cbias[n * 16 + lr];
#pragma unroll
      for (int m = 0; m < 2; ++m)
#pragma unroll
        for (int r = 0; r < 4; ++r)
          Lw[w][m * 16 + 4 * lg + r][n * 16 + lr] = __float2bfloat16(fmaxf(acc[m][n][r] + bv, 0.f));
    }
    // chained k_h = y_h · Wph^T + bph (y_h tile lives only in Lw)
    {
      short8v a2[2][4];
#pragma unroll
      for (int ks = 0; ks < 4; ++ks) {
        a2[0][ks] = *reinterpret_cast<const short8v*>(&Lw[w][lr][ks * 32 + lg * 8]);
        a2[1][ks] = *reinterpret_cast<const short8v*>(&Lw[w][16 + lr][ks * 32 + lg * 8]);
      }
      f32x4 ac2[2][8];
#pragma unroll
      for (int m = 0; m < 2; ++m)
#pragma unroll
        for (int n = 0; n < 8; ++n) ac2[m][n] = z4;
#pragma unroll
      for (int ks = 0; ks < 4; ++ks)
#pragma unroll
        for (int n = 0; n < 8; ++n) {
          short8v b2 = *reinterpret_cast<const short8v*>(Wph + (long)(n * 16 + lr) * 128 + ks * 32 + lg * 8);
          ac2[0][n] = MFMA16(a2[0][ks], b2, ac2[0][n]);
          ac2[1][n] = MFMA16(a2[1][ks], b2, ac2[1][n]);
        }
#pragma unroll
      for (int n = 0; n < 8; ++n) {
        float bv = bph[n * 16 + lr];
#pragma unroll
        for (int m = 0; m < 2; ++m)
#pragma unroll
          for (int r = 0; r < 4; ++r)
            Lw[w][m * 16 + 4 * lg + r][n * 16 + lr] = __float2bfloat16(ac2[m][n][r] + bv);
      }
    }
#pragma unroll
    for (int c = 0; c < 8; ++c) {
      int row_l = c * 4 + lg;
      int sc = R0 + row_l;
      int rp = b * 128 + (sc >> 1);
      int sp = ((sc & 1) << 7) + stk;
      short8v v = *reinterpret_cast<const short8v*>(&Lw[w][row_l][lr * 8]);
      *reinterpret_cast<short8v*>(KH + ((long)rp * 256 + sp) * 128 + lr * 8) = v;
    }
  }
}

// ---------------------------------------------------------------------------
// Final: fused = selfattn·Was^T + bs + crossattn·Wac^T + bc (all f32) -> heads.
// ---------------------------------------------------------------------------
__global__ __launch_bounds__(256) void sf_fin2(const bh* __restrict__ Xs,
                                               const bh* __restrict__ Was, const float* __restrict__ bs,
                                               const bh* __restrict__ Xc,
                                               const bh* __restrict__ Wac, const float* __restrict__ bc,
                                               const float* __restrict__ rw, const float* __restrict__ rb,
                                               const float* __restrict__ cw, const float* __restrict__ cb,
                                               float* __restrict__ out, long off_reg, long off_cla) {
  __shared__ bh Lw[4][32][140];
  __shared__ float hw[3][128];
  const int t = threadIdx.x, lane = t & 63, w = t >> 6;
  const int lr = lane & 15, lg = lane >> 4;
  const long R0 = (long)blockIdx.x * 128 + w * 32;
  const f32x4 z4 = {0.f, 0.f, 0.f, 0.f};
  if (t < 128) { hw[0][t] = rw[t]; hw[1][t] = cw[t]; hw[2][t] = cw[128 + t]; }
  {
    f32x4 acc[2][8];
#pragma unroll
    for (int m = 0; m < 2; ++m)
#pragma unroll
      for (int n = 0; n < 8; ++n) acc[m][n] = z4;
    {
      short8v a[2][4];
#pragma unroll
      for (int ks = 0; ks < 4; ++ks) {
        a[0][ks] = *reinterpret_cast<const short8v*>(Xs + (R0 + lr) * 128 + ks * 32 + lg * 8);
        a[1][ks] = *reinterpret_cast<const short8v*>(Xs + (R0 + 16 + lr) * 128 + ks * 32 + lg * 8);
      }
#pragma unroll
      for (int ks = 0; ks < 4; ++ks)
#pragma unroll
        for (int n = 0; n < 8; ++n) {
          short8v b = *reinterpret_cast<const short8v*>(Was + (long)(n * 16 + lr) * 128 + ks * 32 + lg * 8);
          acc[0][n] = MFMA16(a[0][ks], b, acc[0][n]);
          acc[1][n] = MFMA16(a[1][ks], b, acc[1][n]);
        }
    }
    {
      short8v a[2][4];
#pragma unroll
      for (int ks = 0; ks < 4; ++ks) {
        a[0][ks] = *reinterpret_cast<const short8v*>(Xc + (R0 + lr) * 128 + ks * 32 + lg * 8);
        a[1][ks] = *reinterpret_cast<const short8v*>(Xc + (R0 + 16 + lr) * 128 + ks * 32 + lg * 8);
      }
#pragma unroll
      for (int ks = 0; ks < 4; ++ks)
#pragma unroll
        for (int n = 0; n < 8; ++n) {
          short8v b = *reinterpret_cast<const short8v*>(Wac + (long)(n * 16 + lr) * 128 + ks * 32 + lg * 8);
          acc[0][n] = MFMA16(a[0][ks], b, acc[0][n]);
          acc[1][n] = MFMA16(a[1][ks], b, acc[1][n]);
        }
    }
#pragma unroll
    for (int n = 0; n < 8; ++n) {
      float bv = bs[n * 16 + lr] + bc[n * 16 + lr];
#pragma unroll
      for (int m = 0; m < 2; ++m)
#pragma unroll
        for (int r = 0; r < 4; ++r)
          Lw[w][m * 16 + 4 * lg + r][n * 16 + lr] = __float2bfloat16(acc[m][n][r] + bv);
    }
  }
  __syncthreads();
  {
    const int rr = lane >> 1, hh = lane & 1;
    float d0 = 0.f, d1 = 0.f, d2 = 0.f;
#pragma unroll
    for (int j = 0; j < 8; ++j) {
      short8v v8 = *reinterpret_cast<const short8v*>(&Lw[w][rr][hh * 64 + j * 8]);
      const bh* vv = reinterpret_cast<const bh*>(&v8);
#pragma unroll
      for (int k = 0; k < 8; ++k) {
        float f = __bfloat162float(vv[k]);
        int c = hh * 64 + j * 8 + k;
        d0 = fmaf(f, hw[0][c], d0);
        d1 = fmaf(f, hw[1][c], d1);
        d2 = fmaf(f, hw[2][c], d2);
      }
    }
    d0 += __shfl_xor(d0, 1, 64);
    d1 += __shfl_xor(d1, 1, 64);
    d2 += __shfl_xor(d2, 1, 64);
    if (hh == 0) {
      long row = R0 + rr;
      d0 += rb[0]; d1 += cb[0]; d2 += cb[1];
      float mx = fmaxf(d1, d2);
      float e1 = __expf(d1 - mx), e2 = __expf(d2 - mx);
      float inv = 1.f / (e1 + e2);
      out[off_reg + row] = d0;
      out[off_cla + row * 2] = e1 * inv;
      out[off_cla + row * 2 + 1] = e2 * inv;
    }
  }
}

// ---------------------------------------------------------------------------
extern "C" void kernel_launch(void* const* d_in, const int* in_sizes, int n_in,
                              void* d_out, int out_size, void* d_ws, size_t ws_size,
                              hipStream_t stream) {
  (void)in_sizes; (void)n_in; (void)out_size; (void)ws_size;
  const float* x       = (const float*)d_in[0];
  const float* ta_w_in = (const float*)d_in[2];
  const float* ta_b_in = (const float*)d_in[3];
  const float* ta_w_o  = (const float*)d_in[4];
  const float* ta_b_o  = (const float*)d_in[5];
  const float* conv_w  = (const float*)d_in[6];
  const float* conv_b  = (const float*)d_in[7];
  const float* pl_w    = (const float*)d_in[8];
  const float* pl_b    = (const float*)d_in[9];
  const float* ph_w    = (const float*)d_in[10];
  const float* ph_b    = (const float*)d_in[11];
  const float* as_w_in = (const float*)d_in[12];
  const float* as_b_in = (const float*)d_in[13];
  const float* as_w_o  = (const float*)d_in[14];
  const float* as_b_o  = (const float*)d_in[15];
  const float* ac_w_in = (const float*)d_in[16];
  const float* ac_b_in = (const float*)d_in[17];
  const float* ac_w_o  = (const float*)d_in[18];
  const float* ac_b_o  = (const float*)d_in[19];
  const float* rl_w    = (const float*)d_in[20];
  const float* rl_b    = (const float*)d_in[21];
  const float* cl_w    = (const float*)d_in[22];
  const float* cl_b    = (const float*)d_in[23];
  const float* rf_w    = (const float*)d_in[24];
  const float* rf_b    = (const float*)d_in[25];
  const float* cf_w    = (const float*)d_in[26];
  const float* cf_b    = (const float*)d_in[27];
  float* out = (float*)d_out;

  bh* S0 = (bh*)d_ws;
  bh* S1 = S0 + SF_ELEMS;
  bh* S2 = S1 + SF_ELEMS;
  bh* S3 = S2 + SF_ELEMS;
  bh* S4 = S3 + SF_ELEMS;
  bh* A  = S4 + SF_ELEMS;             // bf16 arena (278528)
  float* PE = (float*)(A + 278528);   // 32768 f32

  dim3 blk(256);
  const int GZ = (int)(SF_ELEMS / 256);

  // 1) weights + PE
  sf_wcvt<<<1216, blk, 0, stream>>>(ta_w_in, ta_w_o, pl_w, ph_w, ac_w_in, ac_w_o,
                                    as_w_in, as_w_o, conv_w, A, PE);
  // 2) z + xh
  sf_buildzx<<<GZ, blk, 0, stream>>>(x, PE, S0, S3);                           // S0=z, S3=xh
  // 3) encoder attention
  sf_attnp<<<2048, blk, 0, stream>>>(S0, S0, A, ta_b_in, S1);                  // S1 = enc attn
  // 4) encdec (y_l->q_l->y_l2->lheads) || convm->k_h
  sf_dec<<<2048, blk, 0, stream>>>(S1, A + 49152, ta_b_o, A + 65536, pl_b,
                                   rl_w, rl_b, cl_w, cl_b, S2, out, 393216L, 524288L,
                                   S3, A + 229376, conv_b, A + 81920, ph_b, S4);
  // 5) cross (Q=q_l, KV=k_h) || self (Q=KV=q_l)
  sf_attnp2<<<4096, blk, 0, stream>>>(S2, S4, A + 98304, ac_b_in, S0,
                                      S2, S2, A + 163840, as_b_in, S3);        // S0=cross, S3=self
  // 6) fused out-projections + heads
  sf_fin2<<<1024, blk, 0, stream>>>(S3, A + 212992, as_b_o, S0, A + 147456, ac_b_o,
                                    rf_w, rf_b, cf_w, cf_b, out, 0L, 131072L);
}

// Round 15
// 470.643 us; speedup vs baseline: 1.6239x; 1.6239x over previous
//
#include <hip/hip_runtime.h>
#include <hip/hip_bf16.h>

// StockFormer forward, MI355X — bf16 MFMA pipeline v5 (reverted-to-best, r11)
// (3-block/CU fused-proj attention + exp2 fold; GEMM-chain fusion; fused heads).
// B=4, S=256, N=128, F=64, D=E=128, NH=4, HD=32, BN=512, M=131072. Output f32.
typedef __attribute__((ext_vector_type(8))) short short8v;   // 8 bf16 (4 VGPR)
typedef __attribute__((ext_vector_type(4))) short short4v;   // 4 bf16 (2 VGPR)
typedef __attribute__((ext_vector_type(4))) float f32x4;
typedef __hip_bfloat16 bh;

constexpr long SF_ELEMS = 131072L * 128;   // elements per ws slot (bf16 -> 32 MiB)
#define MFMA16(a, b, c) __builtin_amdgcn_mfma_f32_16x16x32_bf16((a), (b), (c), 0, 0, 0)

__device__ __forceinline__ short bh_bits(float x) {
  bh h = __float2bfloat16(x);
  return *reinterpret_cast<short*>(&h);
}

// Arena (bf16 elems): 0 ta_w_in | 49152 ta_w_o | 65536 pl | 81920 ph | 98304 ac_w_in |
// 147456 ac_w_o | 163840 as_w_in | 212992 as_w_o | 229376 wrep | 278528 end. Then PE f32.

// ---------------------------------------------------------------------------
__global__ __launch_bounds__(256) void sf_wcvt(const float* __restrict__ s0, const float* __restrict__ s1,
                                               const float* __restrict__ s2, const float* __restrict__ s3,
                                               const float* __restrict__ s4, const float* __restrict__ s5,
                                               const float* __restrict__ s6, const float* __restrict__ s7,
                                               const float* __restrict__ cw,
                                               bh* __restrict__ dst) {
  int i = blockIdx.x * 256 + threadIdx.x;
  float v;
  if      (i <  49152) v = s0[i];
  else if (i <  65536) v = s1[i - 49152];
  else if (i <  81920) v = s2[i - 65536];
  else if (i <  98304) v = s3[i - 81920];
  else if (i < 147456) v = s4[i - 98304];
  else if (i < 163840) v = s5[i - 147456];
  else if (i < 212992) v = s6[i - 163840];
  else if (i < 229376) v = s7[i - 212992];
  else if (i < 278528) {                       // conv_w repack: wrep[tap][dch][ic]
    int j = i - 229376;
    int tap = j >> 14, rem = j & 16383;
    v = cw[rem * 3 + tap];
  } else return;
  dst[i] = __float2bfloat16(v);
}

// ---------------------------------------------------------------------------
__global__ __launch_bounds__(256) void sf_pe(float* __restrict__ pe) {
  int i = blockIdx.x * 256 + threadIdx.x;   // [0, 32768)
  int e = i & 127, s = i >> 7;
  int ii = e >> 1;
  float dv = expf(-0.0719557945041855f * (float)(2 * ii));
  float ang = (float)s * dv;
  pe[i] = (e & 1) ? cosf(ang) : sinf(ang);
}

// ---------------------------------------------------------------------------
// z (xl_cat + PE) and xh (xh_cat) in one pass over x.
// ---------------------------------------------------------------------------
__global__ __launch_bounds__(256) void sf_buildzx(const float* __restrict__ x,
                                                  const float* __restrict__ pe,
                                                  bh* __restrict__ z,
                                                  bh* __restrict__ xh) {
  long i = (long)blockIdx.x * 256 + threadIdx.x;
  if (i >= SF_ELEMS) return;
  int e = (int)(i & 127);
  int s = (int)((i >> 7) & 255);
  int r = (int)(i >> 15);
  int b = r >> 7, stk = r & 127;
  float zv, hv;
  if (e < 64) {
    float val = x[(((long)b * 256 + s) * 128 + stk) * 64 + e];
    zv = val; hv = val;
  } else {
    int f = e - 64;
    int t2 = s >> 1;
    float a0 = x[(((long)b * 256 + 2 * t2) * 128 + stk) * 64 + f];
    float a1 = x[(((long)b * 256 + 2 * t2 + 1) * 128 + stk) * 64 + f];
    zv = 0.5f * (a0 + a1);
    float d = 0.5f * (a0 - a1);
    hv = (s & 1) ? -d : d;
  }
  z[i] = __float2bfloat16(zv + pe[s * 128 + e]);
  xh[i] = __float2bfloat16(hv);
}

// ---------------------------------------------------------------------------
// MFMA linear, wide-store epilogue: Y[M,128] = X[M,128] @ W^T + b
// ---------------------------------------------------------------------------
__global__ __launch_bounds__(256) void sf_lin(const bh* __restrict__ X,
                                              const bh* __restrict__ Wb,
                                              const float* __restrict__ bias,
                                              bh* __restrict__ Y) {
  __shared__ bh Lw[4][32][140];
  const int t = threadIdx.x, lane = t & 63, w = t >> 6;
  const int lr = lane & 15, lg = lane >> 4;
  const long R0 = (long)blockIdx.x * 128 + w * 32;
  const f32x4 z4 = {0.f, 0.f, 0.f, 0.f};
  short8v a[2][4];
#pragma unroll
  for (int ks = 0; ks < 4; ++ks) {
    a[0][ks] = *reinterpret_cast<const short8v*>(X + (R0 + lr) * 128 + ks * 32 + lg * 8);
    a[1][ks] = *reinterpret_cast<const short8v*>(X + (R0 + 16 + lr) * 128 + ks * 32 + lg * 8);
  }
  f32x4 acc[2][8];
#pragma unroll
  for (int m = 0; m < 2; ++m)
#pragma unroll
    for (int n = 0; n < 8; ++n) acc[m][n] = z4;
#pragma unroll
  for (int ks = 0; ks < 4; ++ks) {
#pragma unroll
    for (int n = 0; n < 8; ++n) {
      short8v b = *reinterpret_cast<const short8v*>(Wb + (long)(n * 16 + lr) * 128 + ks * 32 + lg * 8);
      acc[0][n] = MFMA16(a[0][ks], b, acc[0][n]);
      acc[1][n] = MFMA16(a[1][ks], b, acc[1][n]);
    }
  }
#pragma unroll
  for (int n = 0; n < 8; ++n) {
    float bv = bias[n * 16 + lr];
#pragma unroll
    for (int m = 0; m < 2; ++m)
#pragma unroll
      for (int r = 0; r < 4; ++r)
        Lw[w][m * 16 + 4 * lg + r][n * 16 + lr] = __float2bfloat16(acc[m][n][r] + bv);
  }
#pragma unroll
  for (int c = 0; c < 8; ++c) {
    int row_l = c * 4 + lg;
    short8v v = *reinterpret_cast<const short8v*>(&Lw[w][row_l][lr * 8]);
    *reinterpret_cast<short8v*>(Y + (R0 + row_l) * 128 + lr * 8) = v;
  }
}

// ---------------------------------------------------------------------------
// MFMA dilated conv (k=3 pad2 dil2) + ReLU, wide-store epilogue into y_h layout.
// ---------------------------------------------------------------------------
__global__ __launch_bounds__(256) void sf_convm(const bh* __restrict__ Xh,
                                                const bh* __restrict__ Wr,
                                                const float* __restrict__ bias,
                                                bh* __restrict__ Yh) {
  __shared__ bh Lw[4][32][140];
  const int t = threadIdx.x, lane = t & 63, w = t >> 6;
  const int lr = lane & 15, lg = lane >> 4;
  const int bnc = blockIdx.x >> 1;
  const int half = blockIdx.x & 1;
  const int b = bnc >> 7, stk = bnc & 127;
  const int R0 = half * 128 + w * 32;
  const f32x4 z4 = {0.f, 0.f, 0.f, 0.f};
  const short8v zf = {0, 0, 0, 0, 0, 0, 0, 0};
  f32x4 acc[2][8];
#pragma unroll
  for (int m = 0; m < 2; ++m)
#pragma unroll
    for (int n = 0; n < 8; ++n) acc[m][n] = z4;
#pragma unroll
  for (int tap = 0; tap < 3; ++tap) {
    const int shift = 2 * tap - 2;
#pragma unroll
    for (int ks = 0; ks < 4; ++ks) {
      int s0 = R0 + lr + shift;
      int s1 = s0 + 16;
      short8v a0 = zf, a1 = zf;
      if ((unsigned)s0 < 256u)
        a0 = *reinterpret_cast<const short8v*>(Xh + ((long)bnc * 256 + s0) * 128 + ks * 32 + lg * 8);
      if ((unsigned)s1 < 256u)
        a1 = *reinterpret_cast<const short8v*>(Xh + ((long)bnc * 256 + s1) * 128 + ks * 32 + lg * 8);
#pragma unroll
      for (int n = 0; n < 8; ++n) {
        short8v bb = *reinterpret_cast<const short8v*>(Wr + (long)tap * 16384 + (long)(n * 16 + lr) * 128 + ks * 32 + lg * 8);
        acc[0][n] = MFMA16(a0, bb, acc[0][n]);
        acc[1][n] = MFMA16(a1, bb, acc[1][n]);
      }
    }
  }
#pragma unroll
  for (int n = 0; n < 8; ++n) {
    float bv = bias[n * 16 + lr];
#pragma unroll
    for (int m = 0; m < 2; ++m)
#pragma unroll
      for (int r = 0; r < 4; ++r)
        Lw[w][m * 16 + 4 * lg + r][n * 16 + lr] = __float2bfloat16(fmaxf(acc[m][n][r] + bv, 0.f));
  }
#pragma unroll
  for (int c = 0; c < 8; ++c) {
    int row_l = c * 4 + lg;
    int sc = R0 + row_l;
    int rp = b * 128 + (sc >> 1);
    int sp = ((sc & 1) << 7) + stk;
    short8v v = *reinterpret_cast<const short8v*>(&Lw[w][row_l][lr * 8]);
    *reinterpret_cast<short8v*>(Yh + ((long)rp * 256 + sp) * 128 + lr * 8) = v;
  }
}

// ---------------------------------------------------------------------------
// Fused-projection MFMA attention v5: P-tile overlaid on Q staging (52.3 KB LDS
// -> 3 blocks/CU); 1/sqrt(32)*log2(e) folded into Q store; exp2f scores.
// ---------------------------------------------------------------------------
__global__ __launch_bounds__(256) void sf_attnp(const bh* Qsrc, const bh* KVsrc,
                                                const bh* __restrict__ Win,
                                                const float* __restrict__ bin,
                                                bh* __restrict__ O) {
  __shared__ bh Ks[256][36];      // 18.0 KB (krow, d)
  __shared__ bh Vt[32][260];      // 16.3 KB (d, krow)
  __shared__ bh QP[4][64][36];    // 18.0 KB per-wave: Q staging, then P tile
  const int t = threadIdx.x, lane = t & 63, w = t >> 6;
  const int lr = lane & 15, lg = lane >> 4;
  const int bn = blockIdx.x >> 2, h = blockIdx.x & 3;
  const long R0 = (long)bn * 256;
  const int ch = h * 32;
  const f32x4 z4 = {0.f, 0.f, 0.f, 0.f};
  const float SC2 = 0.2550351f;   // (1/sqrt(32)) * log2(e), folded into Q
  // ---- Q projection (64 rows per wave), scaled by SC2 ----
  {
    short8v wq[2][4];
#pragma unroll
    for (int n = 0; n < 2; ++n)
#pragma unroll
      for (int ks = 0; ks < 4; ++ks)
        wq[n][ks] = *reinterpret_cast<const short8v*>(Win + (long)(ch + n * 16 + lr) * 128 + ks * 32 + lg * 8);
#pragma unroll
    for (int m2 = 0; m2 < 4; ++m2) {
      short8v asv[4];
#pragma unroll
      for (int ks = 0; ks < 4; ++ks)
        asv[ks] = *reinterpret_cast<const short8v*>(Qsrc + (R0 + w * 64 + m2 * 16 + lr) * 128 + ks * 32 + lg * 8);
#pragma unroll
      for (int n = 0; n < 2; ++n) {
        f32x4 acc = z4;
#pragma unroll
        for (int ks = 0; ks < 4; ++ks) acc = MFMA16(asv[ks], wq[n][ks], acc);
        float bb = bin[ch + n * 16 + lr];
#pragma unroll
        for (int r = 0; r < 4; ++r)
          QP[w][m2 * 16 + 4 * lg + r][n * 16 + lr] = __float2bfloat16((acc[r] + bb) * SC2);
      }
    }
  }
  // ---- K,V projection (64 rows per wave; shared A-frags) ----
  {
    short8v wk[2][4], wv[2][4];
#pragma unroll
    for (int n = 0; n < 2; ++n)
#pragma unroll
      for (int ks = 0; ks < 4; ++ks) {
        wk[n][ks] = *reinterpret_cast<const short8v*>(Win + (long)(128 + ch + n * 16 + lr) * 128 + ks * 32 + lg * 8);
        wv[n][ks] = *reinterpret_cast<const short8v*>(Win + (long)(256 + ch + n * 16 + lr) * 128 + ks * 32 + lg * 8);
      }
#pragma unroll
    for (int m2 = 0; m2 < 4; ++m2) {
      short8v asv[4];
#pragma unroll
      for (int ks = 0; ks < 4; ++ks)
        asv[ks] = *reinterpret_cast<const short8v*>(KVsrc + (R0 + w * 64 + m2 * 16 + lr) * 128 + ks * 32 + lg * 8);
#pragma unroll
      for (int n = 0; n < 2; ++n) {
        f32x4 ak = z4, av = z4;
#pragma unroll
        for (int ks = 0; ks < 4; ++ks) {
          ak = MFMA16(asv[ks], wk[n][ks], ak);
          av = MFMA16(asv[ks], wv[n][ks], av);
        }
        float bk = bin[128 + ch + n * 16 + lr];
        float bv = bin[256 + ch + n * 16 + lr];
#pragma unroll
        for (int r = 0; r < 4; ++r)
          Ks[w * 64 + m2 * 16 + 4 * lg + r][n * 16 + lr] = __float2bfloat16(ak[r] + bk);
        short4v pv;
#pragma unroll
        for (int r = 0; r < 4; ++r) pv[r] = bh_bits(av[r] + bv);
        *reinterpret_cast<short4v*>(&Vt[n * 16 + lr][w * 64 + m2 * 16 + 4 * lg]) = pv;
      }
    }
  }
  __syncthreads();
  // ---- attention: aq from QP (then QP[w] becomes the per-wave P tile) ----
  short8v aq[4];
#pragma unroll
  for (int mt = 0; mt < 4; ++mt)
    aq[mt] = *reinterpret_cast<const short8v*>(&QP[w][mt * 16 + lr][lg * 8]);
  bh* plp = &QP[w][0][0];   // P tile: (lr, c) at plp[lr*72 + c], wave-local
  f32x4 Oacc[4][2];
  float psum[4] = {0.f, 0.f, 0.f, 0.f};
#pragma unroll
  for (int mt = 0; mt < 4; ++mt) { Oacc[mt][0] = z4; Oacc[mt][1] = z4; }
#pragma unroll
  for (int kt = 0; kt < 4; ++kt) {
    short8v bvf[2][2];
#pragma unroll
    for (int dt = 0; dt < 2; ++dt)
#pragma unroll
      for (int ks = 0; ks < 2; ++ks)
        bvf[dt][ks] = *reinterpret_cast<const short8v*>(&Vt[dt * 16 + lr][kt * 64 + ks * 32 + lg * 8]);
#pragma unroll
    for (int mt = 0; mt < 4; ++mt) {
      f32x4 st[4];
#pragma unroll
      for (int nt = 0; nt < 4; ++nt) {
        short8v bk = *reinterpret_cast<const short8v*>(&Ks[kt * 64 + nt * 16 + lr][lg * 8]);
        st[nt] = MFMA16(bk, aq[mt], z4);     // S^T·SC2 = K·(Q*SC2)^T
      }
      float ps = 0.f;
#pragma unroll
      for (int nt = 0; nt < 4; ++nt) {
        float p0 = exp2f(st[nt][0]);
        float p1 = exp2f(st[nt][1]);
        float p2 = exp2f(st[nt][2]);
        float p3 = exp2f(st[nt][3]);
        ps += (p0 + p1) + (p2 + p3);
        short4v pk;
        pk[0] = bh_bits(p0); pk[1] = bh_bits(p1); pk[2] = bh_bits(p2); pk[3] = bh_bits(p3);
        *reinterpret_cast<short4v*>(&plp[lr * 72 + nt * 16 + 4 * lg]) = pk;
      }
      psum[mt] += ps;
#pragma unroll
      for (int ks = 0; ks < 2; ++ks) {
        short8v ap = *reinterpret_cast<const short8v*>(&plp[lr * 72 + ks * 32 + lg * 8]);
        Oacc[mt][0] = MFMA16(ap, bvf[0][ks], Oacc[mt][0]);
        Oacc[mt][1] = MFMA16(ap, bvf[1][ks], Oacc[mt][1]);
      }
    }
  }
#pragma unroll
  for (int mt = 0; mt < 4; ++mt) {
    float ps = psum[mt];
    ps += __shfl_xor(ps, 16, 64);
    ps += __shfl_xor(ps, 32, 64);
    float inv = 1.f / ps;
#pragma unroll
    for (int r = 0; r < 4; ++r) {
      float invr = __shfl(inv, 4 * lg + r, 64);
      long row = R0 + w * 64 + mt * 16 + 4 * lg + r;
      O[row * 128 + ch + lr]      = __float2bfloat16(Oacc[mt][0][r] * invr);
      O[row * 128 + ch + 16 + lr] = __float2bfloat16(Oacc[mt][1][r] * invr);
    }
  }
}

// ---------------------------------------------------------------------------
// Fused decoder chain: X -> (Wo) y_l -> (pl) q_l [stored] -> (pl) y_l2 -> heads.
// ---------------------------------------------------------------------------
__global__ __launch_bounds__(256) void sf_encdec(const bh* __restrict__ X,
                                                 const bh* __restrict__ Wo, const float* __restrict__ bo,
                                                 const bh* __restrict__ Wpl, const float* __restrict__ bpl,
                                                 const float* __restrict__ rw, const float* __restrict__ rb,
                                                 const float* __restrict__ cw, const float* __restrict__ cb,
                                                 bh* __restrict__ Yq, float* __restrict__ out,
                                                 long off_reg, long off_cla) {
  __shared__ bh Lw[4][32][140];
  __shared__ float hw[3][128];
  const int t = threadIdx.x, lane = t & 63, w = t >> 6;
  const int lr = lane & 15, lg = lane >> 4;
  const long R0 = (long)blockIdx.x * 128 + w * 32;
  const f32x4 z4 = {0.f, 0.f, 0.f, 0.f};
  if (t < 128) { hw[0][t] = rw[t]; hw[1][t] = cw[t]; hw[2][t] = cw[128 + t]; }
  // ---- stage A: y_l = X·Wo^T + bo ----
  {
    short8v a[2][4];
#pragma unroll
    for (int ks = 0; ks < 4; ++ks) {
      a[0][ks] = *reinterpret_cast<const short8v*>(X + (R0 + lr) * 128 + ks * 32 + lg * 8);
      a[1][ks] = *reinterpret_cast<const short8v*>(X + (R0 + 16 + lr) * 128 + ks * 32 + lg * 8);
    }
    f32x4 acc[2][8];
#pragma unroll
    for (int m = 0; m < 2; ++m)
#pragma unroll
      for (int n = 0; n < 8; ++n) acc[m][n] = z4;
#pragma unroll
    for (int ks = 0; ks < 4; ++ks)
#pragma unroll
      for (int n = 0; n < 8; ++n) {
        short8v b = *reinterpret_cast<const short8v*>(Wo + (long)(n * 16 + lr) * 128 + ks * 32 + lg * 8);
        acc[0][n] = MFMA16(a[0][ks], b, acc[0][n]);
        acc[1][n] = MFMA16(a[1][ks], b, acc[1][n]);
      }
#pragma unroll
    for (int n = 0; n < 8; ++n) {
      float bv = bo[n * 16 + lr];
#pragma unroll
      for (int m = 0; m < 2; ++m)
#pragma unroll
        for (int r = 0; r < 4; ++r)
          Lw[w][m * 16 + 4 * lg + r][n * 16 + lr] = __float2bfloat16(acc[m][n][r] + bv);
    }
  }
  // ---- stage B: q_l (store) ; stage C: y_l2 ----
#pragma unroll
  for (int stage = 0; stage < 2; ++stage) {
    short8v a[2][4];
#pragma unroll
    for (int ks = 0; ks < 4; ++ks) {
      a[0][ks] = *reinterpret_cast<const short8v*>(&Lw[w][lr][ks * 32 + lg * 8]);
      a[1][ks] = *reinterpret_cast<const short8v*>(&Lw[w][16 + lr][ks * 32 + lg * 8]);
    }
    f32x4 acc[2][8];
#pragma unroll
    for (int m = 0; m < 2; ++m)
#pragma unroll
      for (int n = 0; n < 8; ++n) acc[m][n] = z4;
#pragma unroll
    for (int ks = 0; ks < 4; ++ks)
#pragma unroll
      for (int n = 0; n < 8; ++n) {
        short8v b = *reinterpret_cast<const short8v*>(Wpl + (long)(n * 16 + lr) * 128 + ks * 32 + lg * 8);
        acc[0][n] = MFMA16(a[0][ks], b, acc[0][n]);
        acc[1][n] = MFMA16(a[1][ks], b, acc[1][n]);
      }
#pragma unroll
    for (int n = 0; n < 8; ++n) {
      float bv = bpl[n * 16 + lr];
#pragma unroll
      for (int m = 0; m < 2; ++m)
#pragma unroll
        for (int r = 0; r < 4; ++r)
          Lw[w][m * 16 + 4 * lg + r][n * 16 + lr] = __float2bfloat16(acc[m][n][r] + bv);
    }
    if (stage == 0) {
#pragma unroll
      for (int c = 0; c < 8; ++c) {
        int row_l = c * 4 + lg;
        short8v v = *reinterpret_cast<const short8v*>(&Lw[w][row_l][lr * 8]);
        *reinterpret_cast<short8v*>(Yq + (R0 + row_l) * 128 + lr * 8) = v;
      }
    }
  }
  __syncthreads();
  // ---- heads on y_l2 tile ----
  {
    const int rr = lane >> 1, hh = lane & 1;
    float d0 = 0.f, d1 = 0.f, d2 = 0.f;
#pragma unroll
    for (int j = 0; j < 8; ++j) {
      short8v v8 = *reinterpret_cast<const short8v*>(&Lw[w][rr][hh * 64 + j * 8]);
      const bh* vv = reinterpret_cast<const bh*>(&v8);
#pragma unroll
      for (int k = 0; k < 8; ++k) {
        float f = __bfloat162float(vv[k]);
        int c = hh * 64 + j * 8 + k;
        d0 = fmaf(f, hw[0][c], d0);
        d1 = fmaf(f, hw[1][c], d1);
        d2 = fmaf(f, hw[2][c], d2);
      }
    }
    d0 += __shfl_xor(d0, 1, 64);
    d1 += __shfl_xor(d1, 1, 64);
    d2 += __shfl_xor(d2, 1, 64);
    if (hh == 0) {
      long row = R0 + rr;
      d0 += rb[0]; d1 += cb[0]; d2 += cb[1];
      float mx = fmaxf(d1, d2);
      float e1 = __expf(d1 - mx), e2 = __expf(d2 - mx);
      float inv = 1.f / (e1 + e2);
      out[off_reg + row] = d0;
      out[off_cla + row * 2] = e1 * inv;
      out[off_cla + row * 2 + 1] = e2 * inv;
    }
  }
}

// ---------------------------------------------------------------------------
// Fused final: fused = X·Was^T + b + Prev (Prev added in f32 at heads read).
// ---------------------------------------------------------------------------
__global__ __launch_bounds__(256) void sf_fin(const bh* __restrict__ X,
                                              const bh* __restrict__ Was, const float* __restrict__ bo,
                                              const bh* __restrict__ Prev,
                                              const float* __restrict__ rw, const float* __restrict__ rb,
                                              const float* __restrict__ cw, const float* __restrict__ cb,
                                              float* __restrict__ out, long off_reg, long off_cla) {
  __shared__ bh Lw[4][32][140];
  __shared__ float hw[3][128];
  const int t = threadIdx.x, lane = t & 63, w = t >> 6;
  const int lr = lane & 15, lg = lane >> 4;
  const long R0 = (long)blockIdx.x * 128 + w * 32;
  const f32x4 z4 = {0.f, 0.f, 0.f, 0.f};
  if (t < 128) { hw[0][t] = rw[t]; hw[1][t] = cw[t]; hw[2][t] = cw[128 + t]; }
  {
    short8v a[2][4];
#pragma unroll
    for (int ks = 0; ks < 4; ++ks) {
      a[0][ks] = *reinterpret_cast<const short8v*>(X + (R0 + lr) * 128 + ks * 32 + lg * 8);
      a[1][ks] = *reinterpret_cast<const short8v*>(X + (R0 + 16 + lr) * 128 + ks * 32 + lg * 8);
    }
    f32x4 acc[2][8];
#pragma unroll
    for (int m = 0; m < 2; ++m)
#pragma unroll
      for (int n = 0; n < 8; ++n) acc[m][n] = z4;
#pragma unroll
    for (int ks = 0; ks < 4; ++ks)
#pragma unroll
      for (int n = 0; n < 8; ++n) {
        short8v b = *reinterpret_cast<const short8v*>(Was + (long)(n * 16 + lr) * 128 + ks * 32 + lg * 8);
        acc[0][n] = MFMA16(a[0][ks], b, acc[0][n]);
        acc[1][n] = MFMA16(a[1][ks], b, acc[1][n]);
      }
#pragma unroll
    for (int n = 0; n < 8; ++n) {
      float bv = bo[n * 16 + lr];
#pragma unroll
      for (int m = 0; m < 2; ++m)
#pragma unroll
        for (int r = 0; r < 4; ++r)
          Lw[w][m * 16 + 4 * lg + r][n * 16 + lr] = __float2bfloat16(acc[m][n][r] + bv);
    }
  }
  __syncthreads();
  {
    const int rr = lane >> 1, hh = lane & 1;
    float d0 = 0.f, d1 = 0.f, d2 = 0.f;
#pragma unroll
    for (int j = 0; j < 8; ++j) {
      short8v v8 = *reinterpret_cast<const short8v*>(&Lw[w][rr][hh * 64 + j * 8]);
      short8v p8 = *reinterpret_cast<const short8v*>(Prev + (R0 + rr) * 128 + hh * 64 + j * 8);
      const bh* vv = reinterpret_cast<const bh*>(&v8);
      const bh* pp = reinterpret_cast<const bh*>(&p8);
#pragma unroll
      for (int k = 0; k < 8; ++k) {
        float f = __bfloat162float(vv[k]) + __bfloat162float(pp[k]);
        int c = hh * 64 + j * 8 + k;
        d0 = fmaf(f, hw[0][c], d0);
        d1 = fmaf(f, hw[1][c], d1);
        d2 = fmaf(f, hw[2][c], d2);
      }
    }
    d0 += __shfl_xor(d0, 1, 64);
    d1 += __shfl_xor(d1, 1, 64);
    d2 += __shfl_xor(d2, 1, 64);
    if (hh == 0) {
      long row = R0 + rr;
      d0 += rb[0]; d1 += cb[0]; d2 += cb[1];
      float mx = fmaxf(d1, d2);
      float e1 = __expf(d1 - mx), e2 = __expf(d2 - mx);
      float inv = 1.f / (e1 + e2);
      out[off_reg + row] = d0;
      out[off_cla + row * 2] = e1 * inv;
      out[off_cla + row * 2 + 1] = e2 * inv;
    }
  }
}

// ---------------------------------------------------------------------------
extern "C" void kernel_launch(void* const* d_in, const int* in_sizes, int n_in,
                              void* d_out, int out_size, void* d_ws, size_t ws_size,
                              hipStream_t stream) {
  (void)in_sizes; (void)n_in; (void)out_size; (void)ws_size;
  const float* x       = (const float*)d_in[0];
  const float* ta_w_in = (const float*)d_in[2];
  const float* ta_b_in = (const float*)d_in[3];
  const float* ta_w_o  = (const float*)d_in[4];
  const float* ta_b_o  = (const float*)d_in[5];
  const float* conv_w  = (const float*)d_in[6];
  const float* conv_b  = (const float*)d_in[7];
  const float* pl_w    = (const float*)d_in[8];
  const float* pl_b    = (const float*)d_in[9];
  const float* ph_w    = (const float*)d_in[10];
  const float* ph_b    = (const float*)d_in[11];
  const float* as_w_in = (const float*)d_in[12];
  const float* as_b_in = (const float*)d_in[13];
  const float* as_w_o  = (const float*)d_in[14];
  const float* as_b_o  = (const float*)d_in[15];
  const float* ac_w_in = (const float*)d_in[16];
  const float* ac_b_in = (const float*)d_in[17];
  const float* ac_w_o  = (const float*)d_in[18];
  const float* ac_b_o  = (const float*)d_in[19];
  const float* rl_w    = (const float*)d_in[20];
  const float* rl_b    = (const float*)d_in[21];
  const float* cl_w    = (const float*)d_in[22];
  const float* cl_b    = (const float*)d_in[23];
  const float* rf_w    = (const float*)d_in[24];
  const float* rf_b    = (const float*)d_in[25];
  const float* cf_w    = (const float*)d_in[26];
  const float* cf_b    = (const float*)d_in[27];
  float* out = (float*)d_out;

  bh* S0 = (bh*)d_ws;
  bh* S1 = S0 + SF_ELEMS;
  bh* S2 = S1 + SF_ELEMS;
  bh* S3 = S2 + SF_ELEMS;
  bh* S4 = S3 + SF_ELEMS;
  bh* A  = S4 + SF_ELEMS;             // bf16 arena (278528)
  float* PE = (float*)(A + 278528);   // 32768 f32

  dim3 blk(256);
  const int GZ = (int)(SF_ELEMS / 256);
  const int GL = 1024;                // 131072 / 128

  sf_wcvt<<<1088, blk, 0, stream>>>(ta_w_in, ta_w_o, pl_w, ph_w, ac_w_in, ac_w_o,
                                    as_w_in, as_w_o, conv_w, A);
  sf_pe<<<128, blk, 0, stream>>>(PE);

  // ---- encoder ----
  sf_buildzx<<<GZ, blk, 0, stream>>>(x, PE, S0, S3);                           // S0 = z, S3 = xh
  sf_attnp<<<2048, blk, 0, stream>>>(S0, S0, A, ta_b_in, S1);                  // S1 = enc attn
  sf_encdec<<<GL, blk, 0, stream>>>(S1, A + 49152, ta_b_o, A + 65536, pl_b,
                                    rl_w, rl_b, cl_w, cl_b, S2, out,
                                    393216L, 524288L);                         // S2 = q_l + lreg/lcla
  sf_convm<<<1024, blk, 0, stream>>>(S3, A + 229376, conv_b, S4);              // S4 = y_h
  sf_lin<<<GL, blk, 0, stream>>>(S4, A + 81920, ph_b, S0);                     // S0 = k_h

  // ---- cross attention (q = q_l, k/v = k_h) ----
  sf_attnp<<<2048, blk, 0, stream>>>(S2, S0, A + 98304, ac_b_in, S3);          // S3 = cross attn
  sf_lin<<<GL, blk, 0, stream>>>(S3, A + 147456, ac_b_o, S4);                  // S4 = a_cross

  // ---- self attention (q/k/v = q_l) ----
  sf_attnp<<<2048, blk, 0, stream>>>(S2, S2, A + 163840, as_b_in, S1);         // S1 = self attn
  sf_fin<<<GL, blk, 0, stream>>>(S1, A + 212992, as_b_o, S4,
                                 rf_w, rf_b, cf_w, cf_b, out, 0L, 131072L);    // reg/cla
}

// Round 16
// 455.707 us; speedup vs baseline: 1.6771x; 1.0328x over previous
//
#include <hip/hip_runtime.h>
#include <hip/hip_bf16.h>

// StockFormer forward, MI355X — bf16 MFMA pipeline v9
// (r11 attention kept verbatim; standalone conv+k_h chain; dual-proj final).
// B=4, S=256, N=128, F=64, D=E=128, NH=4, HD=32, BN=512, M=131072. Output f32.
typedef __attribute__((ext_vector_type(8))) short short8v;   // 8 bf16 (4 VGPR)
typedef __attribute__((ext_vector_type(4))) short short4v;   // 4 bf16 (2 VGPR)
typedef __attribute__((ext_vector_type(4))) float f32x4;
typedef __hip_bfloat16 bh;

constexpr long SF_ELEMS = 131072L * 128;   // elements per ws slot (bf16 -> 32 MiB)
#define MFMA16(a, b, c) __builtin_amdgcn_mfma_f32_16x16x32_bf16((a), (b), (c), 0, 0, 0)

__device__ __forceinline__ short bh_bits(float x) {
  bh h = __float2bfloat16(x);
  return *reinterpret_cast<short*>(&h);
}

// Arena (bf16 elems): 0 ta_w_in | 49152 ta_w_o | 65536 pl | 81920 ph | 98304 ac_w_in |
// 147456 ac_w_o | 163840 as_w_in | 212992 as_w_o | 229376 wrep | 278528 end. Then PE f32.

// ---------------------------------------------------------------------------
__global__ __launch_bounds__(256) void sf_wcvt(const float* __restrict__ s0, const float* __restrict__ s1,
                                               const float* __restrict__ s2, const float* __restrict__ s3,
                                               const float* __restrict__ s4, const float* __restrict__ s5,
                                               const float* __restrict__ s6, const float* __restrict__ s7,
                                               const float* __restrict__ cw,
                                               bh* __restrict__ dst) {
  int i = blockIdx.x * 256 + threadIdx.x;
  float v;
  if      (i <  49152) v = s0[i];
  else if (i <  65536) v = s1[i - 49152];
  else if (i <  81920) v = s2[i - 65536];
  else if (i <  98304) v = s3[i - 81920];
  else if (i < 147456) v = s4[i - 98304];
  else if (i < 163840) v = s5[i - 147456];
  else if (i < 212992) v = s6[i - 163840];
  else if (i < 229376) v = s7[i - 212992];
  else if (i < 278528) {                       // conv_w repack: wrep[tap][dch][ic]
    int j = i - 229376;
    int tap = j >> 14, rem = j & 16383;
    v = cw[rem * 3 + tap];
  } else return;
  dst[i] = __float2bfloat16(v);
}

// ---------------------------------------------------------------------------
__global__ __launch_bounds__(256) void sf_pe(float* __restrict__ pe) {
  int i = blockIdx.x * 256 + threadIdx.x;   // [0, 32768)
  int e = i & 127, s = i >> 7;
  int ii = e >> 1;
  float dv = expf(-0.0719557945041855f * (float)(2 * ii));
  float ang = (float)s * dv;
  pe[i] = (e & 1) ? cosf(ang) : sinf(ang);
}

// ---------------------------------------------------------------------------
// z (xl_cat + PE) and xh (xh_cat) in one pass over x.
// ---------------------------------------------------------------------------
__global__ __launch_bounds__(256) void sf_buildzx(const float* __restrict__ x,
                                                  const float* __restrict__ pe,
                                                  bh* __restrict__ z,
                                                  bh* __restrict__ xh) {
  long i = (long)blockIdx.x * 256 + threadIdx.x;
  if (i >= SF_ELEMS) return;
  int e = (int)(i & 127);
  int s = (int)((i >> 7) & 255);
  int r = (int)(i >> 15);
  int b = r >> 7, stk = r & 127;
  float zv, hv;
  if (e < 64) {
    float val = x[(((long)b * 256 + s) * 128 + stk) * 64 + e];
    zv = val; hv = val;
  } else {
    int f = e - 64;
    int t2 = s >> 1;
    float a0 = x[(((long)b * 256 + 2 * t2) * 128 + stk) * 64 + f];
    float a1 = x[(((long)b * 256 + 2 * t2 + 1) * 128 + stk) * 64 + f];
    zv = 0.5f * (a0 + a1);
    float d = 0.5f * (a0 - a1);
    hv = (s & 1) ? -d : d;
  }
  z[i] = __float2bfloat16(zv + pe[s * 128 + e]);
  xh[i] = __float2bfloat16(hv);
}

// ---------------------------------------------------------------------------
// Fused-projection MFMA attention (r11-verbatim): P-tile overlaid on Q staging;
// 1/sqrt(32)*log2(e) folded into Q store; exp2f scores.
// ---------------------------------------------------------------------------
__global__ __launch_bounds__(256) void sf_attnp(const bh* Qsrc, const bh* KVsrc,
                                                const bh* __restrict__ Win,
                                                const float* __restrict__ bin,
                                                bh* __restrict__ O) {
  __shared__ bh Ks[256][36];      // 18.0 KB (krow, d)
  __shared__ bh Vt[32][260];      // 16.3 KB (d, krow)
  __shared__ bh QP[4][64][36];    // 18.0 KB per-wave: Q staging, then P tile
  const int t = threadIdx.x, lane = t & 63, w = t >> 6;
  const int lr = lane & 15, lg = lane >> 4;
  const int bn = blockIdx.x >> 2, h = blockIdx.x & 3;
  const long R0 = (long)bn * 256;
  const int ch = h * 32;
  const f32x4 z4 = {0.f, 0.f, 0.f, 0.f};
  const float SC2 = 0.2550351f;   // (1/sqrt(32)) * log2(e), folded into Q
  // ---- Q projection (64 rows per wave), scaled by SC2 ----
  {
    short8v wq[2][4];
#pragma unroll
    for (int n = 0; n < 2; ++n)
#pragma unroll
      for (int ks = 0; ks < 4; ++ks)
        wq[n][ks] = *reinterpret_cast<const short8v*>(Win + (long)(ch + n * 16 + lr) * 128 + ks * 32 + lg * 8);
#pragma unroll
    for (int m2 = 0; m2 < 4; ++m2) {
      short8v asv[4];
#pragma unroll
      for (int ks = 0; ks < 4; ++ks)
        asv[ks] = *reinterpret_cast<const short8v*>(Qsrc + (R0 + w * 64 + m2 * 16 + lr) * 128 + ks * 32 + lg * 8);
#pragma unroll
      for (int n = 0; n < 2; ++n) {
        f32x4 acc = z4;
#pragma unroll
        for (int ks = 0; ks < 4; ++ks) acc = MFMA16(asv[ks], wq[n][ks], acc);
        float bb = bin[ch + n * 16 + lr];
#pragma unroll
        for (int r = 0; r < 4; ++r)
          QP[w][m2 * 16 + 4 * lg + r][n * 16 + lr] = __float2bfloat16((acc[r] + bb) * SC2);
      }
    }
  }
  // ---- K,V projection (64 rows per wave; shared A-frags) ----
  {
    short8v wk[2][4], wv[2][4];
#pragma unroll
    for (int n = 0; n < 2; ++n)
#pragma unroll
      for (int ks = 0; ks < 4; ++ks) {
        wk[n][ks] = *reinterpret_cast<const short8v*>(Win + (long)(128 + ch + n * 16 + lr) * 128 + ks * 32 + lg * 8);
        wv[n][ks] = *reinterpret_cast<const short8v*>(Win + (long)(256 + ch + n * 16 + lr) * 128 + ks * 32 + lg * 8);
      }
#pragma unroll
    for (int m2 = 0; m2 < 4; ++m2) {
      short8v asv[4];
#pragma unroll
      for (int ks = 0; ks < 4; ++ks)
        asv[ks] = *reinterpret_cast<const short8v*>(KVsrc + (R0 + w * 64 + m2 * 16 + lr) * 128 + ks * 32 + lg * 8);
#pragma unroll
      for (int n = 0; n < 2; ++n) {
        f32x4 ak = z4, av = z4;
#pragma unroll
        for (int ks = 0; ks < 4; ++ks) {
          ak = MFMA16(asv[ks], wk[n][ks], ak);
          av = MFMA16(asv[ks], wv[n][ks], av);
        }
        float bk = bin[128 + ch + n * 16 + lr];
        float bv = bin[256 + ch + n * 16 + lr];
#pragma unroll
        for (int r = 0; r < 4; ++r)
          Ks[w * 64 + m2 * 16 + 4 * lg + r][n * 16 + lr] = __float2bfloat16(ak[r] + bk);
        short4v pv;
#pragma unroll
        for (int r = 0; r < 4; ++r) pv[r] = bh_bits(av[r] + bv);
        *reinterpret_cast<short4v*>(&Vt[n * 16 + lr][w * 64 + m2 * 16 + 4 * lg]) = pv;
      }
    }
  }
  __syncthreads();
  // ---- attention: aq from QP (then QP[w] becomes the per-wave P tile) ----
  short8v aq[4];
#pragma unroll
  for (int mt = 0; mt < 4; ++mt)
    aq[mt] = *reinterpret_cast<const short8v*>(&QP[w][mt * 16 + lr][lg * 8]);
  bh* plp = &QP[w][0][0];   // P tile: (lr, c) at plp[lr*72 + c], wave-local
  f32x4 Oacc[4][2];
  float psum[4] = {0.f, 0.f, 0.f, 0.f};
#pragma unroll
  for (int mt = 0; mt < 4; ++mt) { Oacc[mt][0] = z4; Oacc[mt][1] = z4; }
#pragma unroll
  for (int kt = 0; kt < 4; ++kt) {
    short8v bvf[2][2];
#pragma unroll
    for (int dt = 0; dt < 2; ++dt)
#pragma unroll
      for (int ks = 0; ks < 2; ++ks)
        bvf[dt][ks] = *reinterpret_cast<const short8v*>(&Vt[dt * 16 + lr][kt * 64 + ks * 32 + lg * 8]);
#pragma unroll
    for (int mt = 0; mt < 4; ++mt) {
      f32x4 st[4];
#pragma unroll
      for (int nt = 0; nt < 4; ++nt) {
        short8v bk = *reinterpret_cast<const short8v*>(&Ks[kt * 64 + nt * 16 + lr][lg * 8]);
        st[nt] = MFMA16(bk, aq[mt], z4);     // S^T·SC2 = K·(Q*SC2)^T
      }
      float ps = 0.f;
#pragma unroll
      for (int nt = 0; nt < 4; ++nt) {
        float p0 = exp2f(st[nt][0]);
        float p1 = exp2f(st[nt][1]);
        float p2 = exp2f(st[nt][2]);
        float p3 = exp2f(st[nt][3]);
        ps += (p0 + p1) + (p2 + p3);
        short4v pk;
        pk[0] = bh_bits(p0); pk[1] = bh_bits(p1); pk[2] = bh_bits(p2); pk[3] = bh_bits(p3);
        *reinterpret_cast<short4v*>(&plp[lr * 72 + nt * 16 + 4 * lg]) = pk;
      }
      psum[mt] += ps;
#pragma unroll
      for (int ks = 0; ks < 2; ++ks) {
        short8v ap = *reinterpret_cast<const short8v*>(&plp[lr * 72 + ks * 32 + lg * 8]);
        Oacc[mt][0] = MFMA16(ap, bvf[0][ks], Oacc[mt][0]);
        Oacc[mt][1] = MFMA16(ap, bvf[1][ks], Oacc[mt][1]);
      }
    }
  }
#pragma unroll
  for (int mt = 0; mt < 4; ++mt) {
    float ps = psum[mt];
    ps += __shfl_xor(ps, 16, 64);
    ps += __shfl_xor(ps, 32, 64);
    float inv = 1.f / ps;
#pragma unroll
    for (int r = 0; r < 4; ++r) {
      float invr = __shfl(inv, 4 * lg + r, 64);
      long row = R0 + w * 64 + mt * 16 + 4 * lg + r;
      O[row * 128 + ch + lr]      = __float2bfloat16(Oacc[mt][0][r] * invr);
      O[row * 128 + ch + 16 + lr] = __float2bfloat16(Oacc[mt][1][r] * invr);
    }
  }
}

// ---------------------------------------------------------------------------
// Standalone conv (k=3 pad2 dil2) + ReLU + chained k_h = y_h·Wph^T + bph.
// y_h tile lives only in the per-wave LDS tile (no barrier: in-order DS).
// Output k_h in y_h's raw-.view() flat layout, wide stores.
// ---------------------------------------------------------------------------
__global__ __launch_bounds__(256) void sf_convkh(const bh* __restrict__ Xh,
                                                 const bh* __restrict__ Wr,
                                                 const float* __restrict__ cbias,
                                                 const bh* __restrict__ Wph,
                                                 const float* __restrict__ bph,
                                                 bh* __restrict__ KH) {
  __shared__ bh Lw[4][32][140];
  const int t = threadIdx.x, lane = t & 63, w = t >> 6;
  const int lr = lane & 15, lg = lane >> 4;
  const int bnc = blockIdx.x >> 1;
  const int half = blockIdx.x & 1;
  const int b = bnc >> 7, stk = bnc & 127;
  const int R0 = half * 128 + w * 32;
  const f32x4 z4 = {0.f, 0.f, 0.f, 0.f};
  const short8v zf = {0, 0, 0, 0, 0, 0, 0, 0};
  f32x4 acc[2][8];
#pragma unroll
  for (int m = 0; m < 2; ++m)
#pragma unroll
    for (int n = 0; n < 8; ++n) acc[m][n] = z4;
#pragma unroll
  for (int tap = 0; tap < 3; ++tap) {
    const int shift = 2 * tap - 2;
#pragma unroll
    for (int ks = 0; ks < 4; ++ks) {
      int s0 = R0 + lr + shift;
      int s1 = s0 + 16;
      short8v a0 = zf, a1 = zf;
      if ((unsigned)s0 < 256u)
        a0 = *reinterpret_cast<const short8v*>(Xh + ((long)bnc * 256 + s0) * 128 + ks * 32 + lg * 8);
      if ((unsigned)s1 < 256u)
        a1 = *reinterpret_cast<const short8v*>(Xh + ((long)bnc * 256 + s1) * 128 + ks * 32 + lg * 8);
#pragma unroll
      for (int n = 0; n < 8; ++n) {
        short8v bb = *reinterpret_cast<const short8v*>(Wr + (long)tap * 16384 + (long)(n * 16 + lr) * 128 + ks * 32 + lg * 8);
        acc[0][n] = MFMA16(a0, bb, acc[0][n]);
        acc[1][n] = MFMA16(a1, bb, acc[1][n]);
      }
    }
  }
#pragma unroll
  for (int n = 0; n < 8; ++n) {
    float bv = cbias[n * 16 + lr];
#pragma unroll
    for (int m = 0; m < 2; ++m)
#pragma unroll
      for (int r = 0; r < 4; ++r)
        Lw[w][m * 16 + 4 * lg + r][n * 16 + lr] = __float2bfloat16(fmaxf(acc[m][n][r] + bv, 0.f));
  }
  // chained k_h = y_h · Wph^T + bph (per-wave tile, no barrier needed)
  {
    short8v a2[2][4];
#pragma unroll
    for (int ks = 0; ks < 4; ++ks) {
      a2[0][ks] = *reinterpret_cast<const short8v*>(&Lw[w][lr][ks * 32 + lg * 8]);
      a2[1][ks] = *reinterpret_cast<const short8v*>(&Lw[w][16 + lr][ks * 32 + lg * 8]);
    }
    f32x4 ac2[2][8];
#pragma unroll
    for (int m = 0; m < 2; ++m)
#pragma unroll
      for (int n = 0; n < 8; ++n) ac2[m][n] = z4;
#pragma unroll
    for (int ks = 0; ks < 4; ++ks)
#pragma unroll
      for (int n = 0; n < 8; ++n) {
        short8v b2 = *reinterpret_cast<const short8v*>(Wph + (long)(n * 16 + lr) * 128 + ks * 32 + lg * 8);
        ac2[0][n] = MFMA16(a2[0][ks], b2, ac2[0][n]);
        ac2[1][n] = MFMA16(a2[1][ks], b2, ac2[1][n]);
      }
#pragma unroll
    for (int n = 0; n < 8; ++n) {
      float bv = bph[n * 16 + lr];
#pragma unroll
      for (int m = 0; m < 2; ++m)
#pragma unroll
        for (int r = 0; r < 4; ++r)
          Lw[w][m * 16 + 4 * lg + r][n * 16 + lr] = __float2bfloat16(ac2[m][n][r] + bv);
    }
  }
#pragma unroll
  for (int c = 0; c < 8; ++c) {
    int row_l = c * 4 + lg;
    int sc = R0 + row_l;
    int rp = b * 128 + (sc >> 1);
    int sp = ((sc & 1) << 7) + stk;
    short8v v = *reinterpret_cast<const short8v*>(&Lw[w][row_l][lr * 8]);
    *reinterpret_cast<short8v*>(KH + ((long)rp * 256 + sp) * 128 + lr * 8) = v;
  }
}

// ---------------------------------------------------------------------------
// Fused decoder chain: X -> (Wo) y_l -> (pl) q_l [stored] -> (pl) y_l2 -> heads.
// ---------------------------------------------------------------------------
__global__ __launch_bounds__(256) void sf_encdec(const bh* __restrict__ X,
                                                 const bh* __restrict__ Wo, const float* __restrict__ bo,
                                                 const bh* __restrict__ Wpl, const float* __restrict__ bpl,
                                                 const float* __restrict__ rw, const float* __restrict__ rb,
                                                 const float* __restrict__ cw, const float* __restrict__ cb,
                                                 bh* __restrict__ Yq, float* __restrict__ out,
                                                 long off_reg, long off_cla) {
  __shared__ bh Lw[4][32][140];
  __shared__ float hw[3][128];
  const int t = threadIdx.x, lane = t & 63, w = t >> 6;
  const int lr = lane & 15, lg = lane >> 4;
  const long R0 = (long)blockIdx.x * 128 + w * 32;
  const f32x4 z4 = {0.f, 0.f, 0.f, 0.f};
  if (t < 128) { hw[0][t] = rw[t]; hw[1][t] = cw[t]; hw[2][t] = cw[128 + t]; }
  // ---- stage A: y_l = X·Wo^T + bo ----
  {
    short8v a[2][4];
#pragma unroll
    for (int ks = 0; ks < 4; ++ks) {
      a[0][ks] = *reinterpret_cast<const short8v*>(X + (R0 + lr) * 128 + ks * 32 + lg * 8);
      a[1][ks] = *reinterpret_cast<const short8v*>(X + (R0 + 16 + lr) * 128 + ks * 32 + lg * 8);
    }
    f32x4 acc[2][8];
#pragma unroll
    for (int m = 0; m < 2; ++m)
#pragma unroll
      for (int n = 0; n < 8; ++n) acc[m][n] = z4;
#pragma unroll
    for (int ks = 0; ks < 4; ++ks)
#pragma unroll
      for (int n = 0; n < 8; ++n) {
        short8v b = *reinterpret_cast<const short8v*>(Wo + (long)(n * 16 + lr) * 128 + ks * 32 + lg * 8);
        acc[0][n] = MFMA16(a[0][ks], b, acc[0][n]);
        acc[1][n] = MFMA16(a[1][ks], b, acc[1][n]);
      }
#pragma unroll
    for (int n = 0; n < 8; ++n) {
      float bv = bo[n * 16 + lr];
#pragma unroll
      for (int m = 0; m < 2; ++m)
#pragma unroll
        for (int r = 0; r < 4; ++r)
          Lw[w][m * 16 + 4 * lg + r][n * 16 + lr] = __float2bfloat16(acc[m][n][r] + bv);
    }
  }
  // ---- stage B: q_l (store) ; stage C: y_l2 ----
#pragma unroll
  for (int stage = 0; stage < 2; ++stage) {
    short8v a[2][4];
#pragma unroll
    for (int ks = 0; ks < 4; ++ks) {
      a[0][ks] = *reinterpret_cast<const short8v*>(&Lw[w][lr][ks * 32 + lg * 8]);
      a[1][ks] = *reinterpret_cast<const short8v*>(&Lw[w][16 + lr][ks * 32 + lg * 8]);
    }
    f32x4 acc[2][8];
#pragma unroll
    for (int m = 0; m < 2; ++m)
#pragma unroll
      for (int n = 0; n < 8; ++n) acc[m][n] = z4;
#pragma unroll
    for (int ks = 0; ks < 4; ++ks)
#pragma unroll
      for (int n = 0; n < 8; ++n) {
        short8v b = *reinterpret_cast<const short8v*>(Wpl + (long)(n * 16 + lr) * 128 + ks * 32 + lg * 8);
        acc[0][n] = MFMA16(a[0][ks], b, acc[0][n]);
        acc[1][n] = MFMA16(a[1][ks], b, acc[1][n]);
      }
#pragma unroll
    for (int n = 0; n < 8; ++n) {
      float bv = bpl[n * 16 + lr];
#pragma unroll
      for (int m = 0; m < 2; ++m)
#pragma unroll
        for (int r = 0; r < 4; ++r)
          Lw[w][m * 16 + 4 * lg + r][n * 16 + lr] = __float2bfloat16(acc[m][n][r] + bv);
    }
    if (stage == 0) {
#pragma unroll
      for (int c = 0; c < 8; ++c) {
        int row_l = c * 4 + lg;
        short8v v = *reinterpret_cast<const short8v*>(&Lw[w][row_l][lr * 8]);
        *reinterpret_cast<short8v*>(Yq + (R0 + row_l) * 128 + lr * 8) = v;
      }
    }
  }
  __syncthreads();
  // ---- heads on y_l2 tile ----
  {
    const int rr = lane >> 1, hh = lane & 1;
    float d0 = 0.f, d1 = 0.f, d2 = 0.f;
#pragma unroll
    for (int j = 0; j < 8; ++j) {
      short8v v8 = *reinterpret_cast<const short8v*>(&Lw[w][rr][hh * 64 + j * 8]);
      const bh* vv = reinterpret_cast<const bh*>(&v8);
#pragma unroll
      for (int k = 0; k < 8; ++k) {
        float f = __bfloat162float(vv[k]);
        int c = hh * 64 + j * 8 + k;
        d0 = fmaf(f, hw[0][c], d0);
        d1 = fmaf(f, hw[1][c], d1);
        d2 = fmaf(f, hw[2][c], d2);
      }
    }
    d0 += __shfl_xor(d0, 1, 64);
    d1 += __shfl_xor(d1, 1, 64);
    d2 += __shfl_xor(d2, 1, 64);
    if (hh == 0) {
      long row = R0 + rr;
      d0 += rb[0]; d1 += cb[0]; d2 += cb[1];
      float mx = fmaxf(d1, d2);
      float e1 = __expf(d1 - mx), e2 = __expf(d2 - mx);
      float inv = 1.f / (e1 + e2);
      out[off_reg + row] = d0;
      out[off_cla + row * 2] = e1 * inv;
      out[off_cla + row * 2 + 1] = e2 * inv;
    }
  }
}

// ---------------------------------------------------------------------------
// Final: fused = selfattn·Was^T + bs + crossattn·Wac^T + bc (all f32) -> heads.
// ---------------------------------------------------------------------------
__global__ __launch_bounds__(256) void sf_fin2(const bh* __restrict__ Xs,
                                               const bh* __restrict__ Was, const float* __restrict__ bs,
                                               const bh* __restrict__ Xc,
                                               const bh* __restrict__ Wac, const float* __restrict__ bc,
                                               const float* __restrict__ rw, const float* __restrict__ rb,
                                               const float* __restrict__ cw, const float* __restrict__ cb,
                                               float* __restrict__ out, long off_reg, long off_cla) {
  __shared__ bh Lw[4][32][140];
  __shared__ float hw[3][128];
  const int t = threadIdx.x, lane = t & 63, w = t >> 6;
  const int lr = lane & 15, lg = lane >> 4;
  const long R0 = (long)blockIdx.x * 128 + w * 32;
  const f32x4 z4 = {0.f, 0.f, 0.f, 0.f};
  if (t < 128) { hw[0][t] = rw[t]; hw[1][t] = cw[t]; hw[2][t] = cw[128 + t]; }
  {
    f32x4 acc[2][8];
#pragma unroll
    for (int m = 0; m < 2; ++m)
#pragma unroll
      for (int n = 0; n < 8; ++n) acc[m][n] = z4;
    {
      short8v a[2][4];
#pragma unroll
      for (int ks = 0; ks < 4; ++ks) {
        a[0][ks] = *reinterpret_cast<const short8v*>(Xs + (R0 + lr) * 128 + ks * 32 + lg * 8);
        a[1][ks] = *reinterpret_cast<const short8v*>(Xs + (R0 + 16 + lr) * 128 + ks * 32 + lg * 8);
      }
#pragma unroll
      for (int ks = 0; ks < 4; ++ks)
#pragma unroll
        for (int n = 0; n < 8; ++n) {
          short8v b = *reinterpret_cast<const short8v*>(Was + (long)(n * 16 + lr) * 128 + ks * 32 + lg * 8);
          acc[0][n] = MFMA16(a[0][ks], b, acc[0][n]);
          acc[1][n] = MFMA16(a[1][ks], b, acc[1][n]);
        }
    }
    {
      short8v a[2][4];
#pragma unroll
      for (int ks = 0; ks < 4; ++ks) {
        a[0][ks] = *reinterpret_cast<const short8v*>(Xc + (R0 + lr) * 128 + ks * 32 + lg * 8);
        a[1][ks] = *reinterpret_cast<const short8v*>(Xc + (R0 + 16 + lr) * 128 + ks * 32 + lg * 8);
      }
#pragma unroll
      for (int ks = 0; ks < 4; ++ks)
#pragma unroll
        for (int n = 0; n < 8; ++n) {
          short8v b = *reinterpret_cast<const short8v*>(Wac + (long)(n * 16 + lr) * 128 + ks * 32 + lg * 8);
          acc[0][n] = MFMA16(a[0][ks], b, acc[0][n]);
          acc[1][n] = MFMA16(a[1][ks], b, acc[1][n]);
        }
    }
#pragma unroll
    for (int n = 0; n < 8; ++n) {
      float bv = bs[n * 16 + lr] + bc[n * 16 + lr];
#pragma unroll
      for (int m = 0; m < 2; ++m)
#pragma unroll
        for (int r = 0; r < 4; ++r)
          Lw[w][m * 16 + 4 * lg + r][n * 16 + lr] = __float2bfloat16(acc[m][n][r] + bv);
    }
  }
  __syncthreads();
  {
    const int rr = lane >> 1, hh = lane & 1;
    float d0 = 0.f, d1 = 0.f, d2 = 0.f;
#pragma unroll
    for (int j = 0; j < 8; ++j) {
      short8v v8 = *reinterpret_cast<const short8v*>(&Lw[w][rr][hh * 64 + j * 8]);
      const bh* vv = reinterpret_cast<const bh*>(&v8);
#pragma unroll
      for (int k = 0; k < 8; ++k) {
        float f = __bfloat162float(vv[k]);
        int c = hh * 64 + j * 8 + k;
        d0 = fmaf(f, hw[0][c], d0);
        d1 = fmaf(f, hw[1][c], d1);
        d2 = fmaf(f, hw[2][c], d2);
      }
    }
    d0 += __shfl_xor(d0, 1, 64);
    d1 += __shfl_xor(d1, 1, 64);
    d2 += __shfl_xor(d2, 1, 64);
    if (hh == 0) {
      long row = R0 + rr;
      d0 += rb[0]; d1 += cb[0]; d2 += cb[1];
      float mx = fmaxf(d1, d2);
      float e1 = __expf(d1 - mx), e2 = __expf(d2 - mx);
      float inv = 1.f / (e1 + e2);
      out[off_reg + row] = d0;
      out[off_cla + row * 2] = e1 * inv;
      out[off_cla + row * 2 + 1] = e2 * inv;
    }
  }
}

// ---------------------------------------------------------------------------
extern "C" void kernel_launch(void* const* d_in, const int* in_sizes, int n_in,
                              void* d_out, int out_size, void* d_ws, size_t ws_size,
                              hipStream_t stream) {
  (void)in_sizes; (void)n_in; (void)out_size; (void)ws_size;
  const float* x       = (const float*)d_in[0];
  const float* ta_w_in = (const float*)d_in[2];
  const float* ta_b_in = (const float*)d_in[3];
  const float* ta_w_o  = (const float*)d_in[4];
  const float* ta_b_o  = (const float*)d_in[5];
  const float* conv_w  = (const float*)d_in[6];
  const float* conv_b  = (const float*)d_in[7];
  const float* pl_w    = (const float*)d_in[8];
  const float* pl_b    = (const float*)d_in[9];
  const float* ph_w    = (const float*)d_in[10];
  const float* ph_b    = (const float*)d_in[11];
  const float* as_w_in = (const float*)d_in[12];
  const float* as_b_in = (const float*)d_in[13];
  const float* as_w_o  = (const float*)d_in[14];
  const float* as_b_o  = (const float*)d_in[15];
  const float* ac_w_in = (const float*)d_in[16];
  const float* ac_b_in = (const float*)d_in[17];
  const float* ac_w_o  = (const float*)d_in[18];
  const float* ac_b_o  = (const float*)d_in[19];
  const float* rl_w    = (const float*)d_in[20];
  const float* rl_b    = (const float*)d_in[21];
  const float* cl_w    = (const float*)d_in[22];
  const float* cl_b    = (const float*)d_in[23];
  const float* rf_w    = (const float*)d_in[24];
  const float* rf_b    = (const float*)d_in[25];
  const float* cf_w    = (const float*)d_in[26];
  const float* cf_b    = (const float*)d_in[27];
  float* out = (float*)d_out;

  bh* S0 = (bh*)d_ws;
  bh* S1 = S0 + SF_ELEMS;
  bh* S2 = S1 + SF_ELEMS;
  bh* S3 = S2 + SF_ELEMS;
  bh* S4 = S3 + SF_ELEMS;
  bh* A  = S4 + SF_ELEMS;             // bf16 arena (278528)
  float* PE = (float*)(A + 278528);   // 32768 f32

  dim3 blk(256);
  const int GZ = (int)(SF_ELEMS / 256);
  const int GL = 1024;                // 131072 / 128

  sf_wcvt<<<1088, blk, 0, stream>>>(ta_w_in, ta_w_o, pl_w, ph_w, ac_w_in, ac_w_o,
                                    as_w_in, as_w_o, conv_w, A);
  sf_pe<<<128, blk, 0, stream>>>(PE);

  // ---- encoder ----
  sf_buildzx<<<GZ, blk, 0, stream>>>(x, PE, S0, S3);                           // S0 = z, S3 = xh
  sf_attnp<<<2048, blk, 0, stream>>>(S0, S0, A, ta_b_in, S1);                  // S1 = enc attn
  sf_encdec<<<GL, blk, 0, stream>>>(S1, A + 49152, ta_b_o, A + 65536, pl_b,
                                    rl_w, rl_b, cl_w, cl_b, S2, out,
                                    393216L, 524288L);                         // S2 = q_l + lreg/lcla
  sf_convkh<<<1024, blk, 0, stream>>>(S3, A + 229376, conv_b, A + 81920, ph_b, S0); // S0 = k_h

  // ---- cross attention (q = q_l, k/v = k_h) ----
  sf_attnp<<<2048, blk, 0, stream>>>(S2, S0, A + 98304, ac_b_in, S3);          // S3 = cross attn

  // ---- self attention (q/k/v = q_l) ----
  sf_attnp<<<2048, blk, 0, stream>>>(S2, S2, A + 163840, as_b_in, S1);         // S1 = self attn

  // ---- fused out-projections + heads ----
  sf_fin2<<<GL, blk, 0, stream>>>(S1, A + 212992, as_b_o, S3, A + 147456, ac_b_o,
                                  rf_w, rf_b, cf_w, cf_b, out, 0L, 131072L);   // reg/cla
}